// Round 9
// baseline (73.651 us; speedup 1.0000x reference)
//
#include <hip/hip_runtime.h>

#define NN 400
#define FF 240
#define CC 32
#define NIN 304   // F + 2C
#define LL 1440

// ---------------------------------------------------------------------------
// K1: P[i][c] = sb[c] + sum_f x[i][f]*sw[f*C+c] ; Q likewise with sw[F:2F].
// grid = N blocks, 256 threads.
// ---------------------------------------------------------------------------
__global__ __launch_bounds__(256) void pq_kernel(
    const float* __restrict__ x, const float* __restrict__ sw,
    const float* __restrict__ sb, float* __restrict__ P, float* __restrict__ Q) {
    const int i   = blockIdx.x;
    const int t   = threadIdx.x;
    const int c   = t & 31;
    const int isQ = (t >> 5) & 1;
    const int g   = t >> 6;            // 0..3, 60 f each
    const float* wb = sw + (isQ ? FF * CC : 0) + c;
    float acc = (!isQ && g == 0) ? sb[c] : 0.0f;
    const float* xr = x + i * FF;
    const int f0 = g * 60;
    #pragma unroll 4
    for (int f = f0; f < f0 + 60; ++f) acc += xr[f] * wb[f * CC];
    __shared__ float red[4][64];
    red[g][t & 63] = acc;
    __syncthreads();
    if (t < 64) {
        const float s = red[0][t] + red[1][t] + red[2][t] + red[3][t];
        if (t >= 32) Q[i * CC + (t & 31)] = s;
        else         P[i * CC + t] = s;
    }
}

// ---------------------------------------------------------------------------
// K2/K3: one 512-thread block per row b (8 waves, <=128 VGPR -> 2 blocks/CU
// -> all 400 blocks co-resident in ONE round, 16 waves/CU). XCD-swizzled b.
// rcf over all 400 k (7 iterations of 64 pairs, gathers hoisted 7-deep for
// MLP), agg reduced in LDS, node model inline, then (layer 1) next P/Q.
// pg = t>>3 pair-group in [0,64), l = t&7 channel quad.
// ---------------------------------------------------------------------------
template<bool WRITE_E, bool DO_PQ>
__global__ __launch_bounds__(512, 4) void rcf_node(
    const float* __restrict__ P, const float* __restrict__ Q,
    const float* __restrict__ e, const float* __restrict__ a,
    const float* __restrict__ sw_tail,   // sw + 480*CC : rows [w1 ; w2]
    const float* __restrict__ aiw, const float* __restrict__ aib,
    const float* __restrict__ ajw, const float* __restrict__ ajb,
    const float* __restrict__ ew, const float* __restrict__ eb,
    float* __restrict__ e_out,
    const float* __restrict__ xin, const float* __restrict__ nw,
    const float* __restrict__ nb,
    const float* __restrict__ sw2, const float* __restrict__ sb2,
    float* __restrict__ xout, float* __restrict__ Pout, float* __restrict__ Qout) {
    // XCD-aware swizzle: 400 = 8 XCDs * 50 rows, bijective
    const int bid = blockIdx.x;
    const int b   = (bid & 7) * 50 + (bid >> 3);
    const int t  = threadIdx.x;
    const int pg = t >> 3, l = t & 7, c0 = l * 4;

    __shared__ float smem[5664];
    float* red  = smem;          // 4608 = 128*36 (rcf reduce; later redn/red2)
    float* v    = smem + 4608;   // 304 (node input vector)
    float* xs   = smem + 4912;   // 240 (node output row)
    float* part = smem + 5152;   // 512 (stage-1 agg partials)
    float* redn = smem;          // 8*240 = 1920 (overlays red)
    float* red2 = smem;          // 8*64  = 512  (overlays red)

    if (t < FF) v[t] = xin[b * FF + t];   // stage x-row early (hidden under rcf)

    // ---- hoisted gather/row loads: 28-deep MLP on the latency-bound lines ----
    float e_f4[7], e_r4[7], a_bk4[7], a_kb4[7];
    int kk[7];
    #pragma unroll
    for (int it = 0; it < 7; ++it) {
        const int off = it * 64 + pg;
        kk[it] = (off < NN) ? off : 0;
        e_f4[it]  = e[b * NN + kk[it]];
        e_r4[it]  = e[kk[it] * NN + b];
        a_bk4[it] = a[b * NN + kk[it]];
        a_kb4[it] = a[kk[it] * NN + b];
    }

    // ---- rcf: both gate directions for row b over all k ----
    float w1v[4], w2v[4], wiv[4], wjv[4], wev[4], Pb[4], Qb[4];
    *(float4*)w1v = *(const float4*)(sw_tail + c0);
    *(float4*)w2v = *(const float4*)(sw_tail + CC + c0);
    *(float4*)wiv = *(const float4*)(aiw + c0);
    *(float4*)wjv = *(const float4*)(ajw + c0);
    if (WRITE_E) *(float4*)wev = *(const float4*)(ew + c0);
    *(float4*)Pb = *(const float4*)(P + b * CC + c0);
    *(float4*)Qb = *(const float4*)(Q + b * CC + c0);
    const float bi = aib[0], bj = ajb[0];
    const float be = WRITE_E ? eb[0] : 0.0f;

    float acc_i[4] = {0, 0, 0, 0}, acc_j[4] = {0, 0, 0, 0};
    #pragma unroll
    for (int it = 0; it < 7; ++it) {
        const int off = it * 64 + pg;
        const bool valid = off < NN;
        const int k = kk[it];
        float Qk[4], Pk[4];
        *(float4*)Qk = *(const float4*)(Q + k * CC + c0);
        *(float4*)Pk = *(const float4*)(P + k * CC + c0);
        const float e_f = e_f4[it], e_r = e_r4[it];
        const float a_bk = a_bk4[it], a_kb = a_kb4[it];
        float sr[4], sc[4];
        #pragma unroll
        for (int q = 0; q < 4; ++q) {
            sr[q] = fmaxf(Pb[q] + Qk[q] + e_f * w1v[q] + e_r * w2v[q], 0.0f) * a_bk;
            sc[q] = fmaxf(Pk[q] + Qb[q] + e_r * w1v[q] + e_f * w2v[q], 0.0f) * a_kb;
        }
        float d_i = sr[0] * wiv[0] + sr[1] * wiv[1] + sr[2] * wiv[2] + sr[3] * wiv[3];
        float d_j = sc[0] * wjv[0] + sc[1] * wjv[1] + sc[2] * wjv[2] + sc[3] * wjv[3];
        float d_e = WRITE_E ? (sr[0] * wev[0] + sr[1] * wev[1] + sr[2] * wev[2] + sr[3] * wev[3]) : 0.0f;
        #pragma unroll
        for (int m = 1; m < 8; m <<= 1) {
            d_i += __shfl_xor(d_i, m);
            d_j += __shfl_xor(d_j, m);
            if (WRITE_E) d_e += __shfl_xor(d_e, m);
        }
        const float gi = valid ? __fdividef(1.0f, 1.0f + __expf(-(d_i + bi))) : 0.0f;
        const float gj = valid ? __fdividef(1.0f, 1.0f + __expf(-(d_j + bj))) : 0.0f;
        #pragma unroll
        for (int q = 0; q < 4; ++q) {
            acc_i[q] += gi * sr[q];
            acc_j[q] += gj * sc[q];
        }
        if (WRITE_E && l == 0 && valid) e_out[b * NN + k] = d_e + be;
    }
    #pragma unroll
    for (int q = 0; q < 4; ++q) {
        red[pg * 36 + c0 + q]         = acc_i[q];
        red[(64 + pg) * 36 + c0 + q]  = acc_j[q];
    }
    __syncthreads();
    // stage-1: 512 threads each sum 8 pair-groups
    {
        const int c = t & 31, sg = (t >> 5) & 7, which = t >> 8;
        float s = 0.0f;
        #pragma unroll
        for (int g2 = sg * 8; g2 < sg * 8 + 8; ++g2)
            s += red[(which * 64 + g2) * 36 + c];
        part[t] = s;
    }
    __syncthreads();
    // stage-2: agg_i (t<32) / agg_j (t in 32..63) land directly in v[240+t]
    if (t < 64) {
        const int which = t >> 5, c = t & 31;
        float s = 0.0f;
        #pragma unroll
        for (int sg = 0; sg < 8; ++sg) s += part[which * 256 + sg * 32 + c];
        v[FF + t] = s;
    }
    __syncthreads();

    // ---- node model: xout[b] = nb + v @ nw  (304 x 240), 480 threads ----
    {
        const int fg = t % 60, h = t / 60;   // h in [0,8), 38 k each
        if (t < 480) {
            const int f0 = fg * 4;
            float4 acc = make_float4(0.f, 0.f, 0.f, 0.f);
            const int k0 = h * 38;
            #pragma unroll
            for (int k = k0; k < k0 + 38; ++k) {
                const float vk = v[k];
                const float4 w = *(const float4*)(nw + k * FF + f0);
                acc.x += vk * w.x; acc.y += vk * w.y;
                acc.z += vk * w.z; acc.w += vk * w.w;
            }
            *(float4*)(redn + h * 240 + f0) = acc;
        }
    }
    __syncthreads();
    if (t < FF) {
        float r = nb[t];
        #pragma unroll
        for (int h = 0; h < 8; ++h) r += redn[h * 240 + t];
        xout[b * FF + t] = r;
        xs[t] = r;
    }
    if (DO_PQ) {
        __syncthreads();
        const int c = t & 31, isQ = (t >> 5) & 1, g = t >> 6;   // g in [0,8)
        const float* wb = sw2 + (isQ ? FF * CC : 0) + c;
        float acc = (!isQ && g == 0) ? sb2[c] : 0.0f;
        const int f0 = g * 30;
        #pragma unroll
        for (int f = f0; f < f0 + 30; ++f) acc += xs[f] * wb[f * CC];
        red2[g * 64 + (t & 63)] = acc;
        __syncthreads();
        if (t < 64) {
            float s = 0.0f;
            #pragma unroll
            for (int g2 = 0; g2 < 8; ++g2) s += red2[g2 * 64 + t];
            if (t >= 32) Qout[b * CC + (t & 31)] = s;
            else         Pout[b * CC + t] = s;
        }
    }
}

// ---------------------------------------------------------------------------
// K4: out[i][l] = db[l] + sum_f x2[i][f]*dw[f*L+l], 8 rows/block.
// x2 reads are block-uniform -> scalar (s_load) pipe, no LDS at all; the
// only vector traffic is the coalesced dw column slice (L2-resident).
// grid = (N/8, 6) blocks, 256 threads.
// ---------------------------------------------------------------------------
__global__ __launch_bounds__(256) void dense_kernel(
    const float* __restrict__ x, const float* __restrict__ dw,
    const float* __restrict__ db, float* __restrict__ out) {
    const int i0 = blockIdx.x * 8;
    const int l  = blockIdx.y * 256 + threadIdx.x;
    if (l >= LL) return;
    float acc[8];
    const float d = db[l];
    #pragma unroll
    for (int r = 0; r < 8; ++r) acc[r] = d;
    #pragma unroll 4
    for (int f = 0; f < FF; ++f) {
        const float w = dw[f * LL + l];
        #pragma unroll
        for (int r = 0; r < 8; ++r) acc[r] += x[(i0 + r) * FF + f] * w;
    }
    #pragma unroll
    for (int r = 0; r < 8; ++r) out[(i0 + r) * LL + l] = acc[r];
}

extern "C" void kernel_launch(void* const* d_in, const int* in_sizes, int n_in,
                              void* d_out, int out_size, void* d_ws, size_t ws_size,
                              hipStream_t stream) {
    const float* x  = (const float*)d_in[0];
    const float* a  = (const float*)d_in[1];
    const float* e0 = (const float*)d_in[2];

    const float* c1_sw  = (const float*)d_in[3];
    const float* c1_sb  = (const float*)d_in[4];
    const float* c1_aiw = (const float*)d_in[5];
    const float* c1_aib = (const float*)d_in[6];
    const float* c1_ajw = (const float*)d_in[7];
    const float* c1_ajb = (const float*)d_in[8];
    const float* c1_nw  = (const float*)d_in[9];
    const float* c1_nb  = (const float*)d_in[10];
    const float* c1_ew  = (const float*)d_in[11];
    const float* c1_eb  = (const float*)d_in[12];

    const float* c2_sw  = (const float*)d_in[13];
    const float* c2_sb  = (const float*)d_in[14];
    const float* c2_aiw = (const float*)d_in[15];
    const float* c2_aib = (const float*)d_in[16];
    const float* c2_ajw = (const float*)d_in[17];
    const float* c2_ajb = (const float*)d_in[18];
    const float* c2_nw  = (const float*)d_in[19];
    const float* c2_nb  = (const float*)d_in[20];
    // d_in[21]/d_in[22] (c2_ew/c2_eb): layer-2 edge output is dead code
    const float* dw = (const float*)d_in[23];
    const float* db = (const float*)d_in[24];

    float* ws = (float*)d_ws;
    float* P1 = ws;                 // 12800
    float* Q1 = ws + 12800;         // 12800
    float* P2 = ws + 25600;         // 12800
    float* Q2 = ws + 38400;         // 12800
    float* x1 = ws + 51200;         // 96000
    float* x2 = ws + 147200;        // 96000
    float* e1 = ws + 243200;        // 160000

    float* out = (float*)d_out;

    // K1: layer-1 P/Q projection
    pq_kernel<<<NN, 256, 0, stream>>>(x, c1_sw, c1_sb, P1, Q1);

    // K2: layer-1 rcf + node model + layer-2 P/Q (all per-row, in-block)
    rcf_node<true, true><<<NN, 512, 0, stream>>>(
        P1, Q1, e0, a, c1_sw + 480 * CC,
        c1_aiw, c1_aib, c1_ajw, c1_ajb, c1_ew, c1_eb, e1,
        x, c1_nw, c1_nb, c2_sw, c2_sb, x1, P2, Q2);

    // K3: layer-2 rcf + node model (no e_out, no next PQ)
    rcf_node<false, false><<<NN, 512, 0, stream>>>(
        P2, Q2, e1, a, c2_sw + 480 * CC,
        c2_aiw, c2_aib, c2_ajw, c2_ajb, nullptr, nullptr, nullptr,
        x1, c2_nw, c2_nb, nullptr, nullptr, x2, nullptr, nullptr);

    // K4: final dense
    dense_kernel<<<dim3(NN / 8, 6), 256, 0, stream>>>(x2, dw, db, out);
}

// Round 10
// 63.819 us; speedup vs baseline: 1.1541x; 1.1541x over previous
//
#include <hip/hip_runtime.h>

#define NN 400
#define FF 240
#define CC 32
#define NIN 304   // F + 2C
#define LL 1440

// ---------------------------------------------------------------------------
// K1: P/Q projection, 2 rows per block (sw read once per 2 rows).
// grid = 200 blocks, 256 threads.
// ---------------------------------------------------------------------------
__global__ __launch_bounds__(256) void pq_kernel(
    const float* __restrict__ x, const float* __restrict__ sw,
    const float* __restrict__ sb, float* __restrict__ P, float* __restrict__ Q) {
    const int i0  = blockIdx.x * 2;
    const int t   = threadIdx.x;
    const int c   = t & 31;
    const int isQ = (t >> 5) & 1;
    const int g   = t >> 6;            // 0..3, 60 f each
    const float* wb = sw + (isQ ? FF * CC : 0) + c;
    const float bias = (!isQ && g == 0) ? sb[c] : 0.0f;
    float accA = bias, accB = bias;
    const float* xrA = x + i0 * FF;
    const float* xrB = x + (i0 + 1) * FF;
    const int f0 = g * 60;
    #pragma unroll 4
    for (int f = f0; f < f0 + 60; ++f) {
        const float w = wb[f * CC];
        accA += xrA[f] * w;
        accB += xrB[f] * w;
    }
    __shared__ float red[4][128];
    red[g][t & 63]        = accA;
    red[g][64 + (t & 63)] = accB;
    __syncthreads();
    if (t < 128) {
        const int row = t >> 6, slot = t & 63;
        const float s = red[0][row * 64 + slot] + red[1][row * 64 + slot]
                      + red[2][row * 64 + slot] + red[3][row * 64 + slot];
        const int i = i0 + row;
        if (slot >= 32) Q[i * CC + (slot & 31)] = s;
        else            P[i * CC + slot] = s;
    }
}

// ---------------------------------------------------------------------------
// K2/K3: one 1024-thread block per TWO rows (base, base+1). XCD-swizzled so
// an XCD's 25 blocks own 50 consecutive rows (column gather lines shared in
// that XCD's L2; rows base/base+1 share the same 64B column lines).
// Per row-phase: rcf over all 400 k (4 its of 128 pairs, gathers hoisted),
// agg reduced in LDS. Then ONE node tail + ONE PQ tail for both rows, with
// nw / sw2 read once per block (2x weight-traffic amortization vs R8).
// pg = t>>3 pair-group in [0,128), l = t&7 channel quad.
// ---------------------------------------------------------------------------
template<bool WRITE_E, bool DO_PQ>
__global__ __launch_bounds__(1024) void rcf_node(
    const float* __restrict__ P, const float* __restrict__ Q,
    const float* __restrict__ e, const float* __restrict__ a,
    const float* __restrict__ sw_tail,   // sw + 480*CC : rows [w1 ; w2]
    const float* __restrict__ aiw, const float* __restrict__ aib,
    const float* __restrict__ ajw, const float* __restrict__ ajb,
    const float* __restrict__ ew, const float* __restrict__ eb,
    float* __restrict__ e_out,
    const float* __restrict__ xin, const float* __restrict__ nw,
    const float* __restrict__ nb,
    const float* __restrict__ sw2, const float* __restrict__ sb2,
    float* __restrict__ xout, float* __restrict__ Pout, float* __restrict__ Qout) {
    // 200 blocks: (bid&7) selects XCD cluster of 50 rows; (bid>>3) in [0,25)
    const int bid  = blockIdx.x;
    const int base = (bid & 7) * 50 + (bid >> 3) * 2;
    const int t  = threadIdx.x;
    const int pg = t >> 3, l = t & 7, c0 = l * 4;

    __shared__ float smem[10816];
    float* red  = smem;           // 9216 = 256*36 (rcf reduce; overlaid later)
    float* vA   = smem + 9216;    // 304
    float* vB   = smem + 9520;    // 304
    float* xsA  = smem + 9824;    // 240
    float* xsB  = smem + 10064;   // 240
    float* part = smem + 10304;   // 512
    float* redn = smem;           // 2*16*240 = 7680 (overlays red)
    float* red2 = smem;           // 2*16*64  = 2048 (overlays red)

    if (t < FF) {                 // stage both x-rows early
        vA[t] = xin[base * FF + t];
        vB[t] = xin[(base + 1) * FF + t];
    }

    // weights shared across both row-phases
    float w1v[4], w2v[4], wiv[4], wjv[4], wev[4];
    *(float4*)w1v = *(const float4*)(sw_tail + c0);
    *(float4*)w2v = *(const float4*)(sw_tail + CC + c0);
    *(float4*)wiv = *(const float4*)(aiw + c0);
    *(float4*)wjv = *(const float4*)(ajw + c0);
    if (WRITE_E) *(float4*)wev = *(const float4*)(ew + c0);
    const float bi = aib[0], bj = ajb[0];
    const float be = WRITE_E ? eb[0] : 0.0f;

    for (int rp = 0; rp < 2; ++rp) {
        const int b = base + rp;
        float* vcur = rp ? vB : vA;

        // hoisted gather/row loads: 16-deep MLP on the latency-bound lines
        float e_f4[4], e_r4[4], a_bk4[4], a_kb4[4];
        int kk[4];
        #pragma unroll
        for (int it = 0; it < 4; ++it) {
            const int off = it * 128 + pg;
            kk[it] = (off < NN) ? off : 0;
            e_f4[it]  = e[b * NN + kk[it]];
            e_r4[it]  = e[kk[it] * NN + b];
            a_bk4[it] = a[b * NN + kk[it]];
            a_kb4[it] = a[kk[it] * NN + b];
        }

        float Pb[4], Qb[4];
        *(float4*)Pb = *(const float4*)(P + b * CC + c0);
        *(float4*)Qb = *(const float4*)(Q + b * CC + c0);

        float acc_i[4] = {0, 0, 0, 0}, acc_j[4] = {0, 0, 0, 0};
        #pragma unroll
        for (int it = 0; it < 4; ++it) {
            const int off = it * 128 + pg;
            const bool valid = off < NN;
            const int k = kk[it];
            float Qk[4], Pk[4];
            *(float4*)Qk = *(const float4*)(Q + k * CC + c0);
            *(float4*)Pk = *(const float4*)(P + k * CC + c0);
            const float e_f = e_f4[it], e_r = e_r4[it];
            const float a_bk = a_bk4[it], a_kb = a_kb4[it];
            float sr[4], sc[4];
            #pragma unroll
            for (int q = 0; q < 4; ++q) {
                sr[q] = fmaxf(Pb[q] + Qk[q] + e_f * w1v[q] + e_r * w2v[q], 0.0f) * a_bk;
                sc[q] = fmaxf(Pk[q] + Qb[q] + e_r * w1v[q] + e_f * w2v[q], 0.0f) * a_kb;
            }
            float d_i = sr[0] * wiv[0] + sr[1] * wiv[1] + sr[2] * wiv[2] + sr[3] * wiv[3];
            float d_j = sc[0] * wjv[0] + sc[1] * wjv[1] + sc[2] * wjv[2] + sc[3] * wjv[3];
            float d_e = WRITE_E ? (sr[0] * wev[0] + sr[1] * wev[1] + sr[2] * wev[2] + sr[3] * wev[3]) : 0.0f;
            #pragma unroll
            for (int m = 1; m < 8; m <<= 1) {
                d_i += __shfl_xor(d_i, m);
                d_j += __shfl_xor(d_j, m);
                if (WRITE_E) d_e += __shfl_xor(d_e, m);
            }
            const float gi = valid ? __fdividef(1.0f, 1.0f + __expf(-(d_i + bi))) : 0.0f;
            const float gj = valid ? __fdividef(1.0f, 1.0f + __expf(-(d_j + bj))) : 0.0f;
            #pragma unroll
            for (int q = 0; q < 4; ++q) {
                acc_i[q] += gi * sr[q];
                acc_j[q] += gj * sc[q];
            }
            if (WRITE_E && l == 0 && valid) e_out[b * NN + k] = d_e + be;
        }
        #pragma unroll
        for (int q = 0; q < 4; ++q) {
            red[pg * 36 + c0 + q]          = acc_i[q];
            red[(128 + pg) * 36 + c0 + q]  = acc_j[q];
        }
        __syncthreads();
        // stage-1: 512 threads each sum 16 pair-groups
        if (t < 512) {
            const int c = t & 31, sg = (t >> 5) & 7, which = t >> 8;
            float s = 0.0f;
            #pragma unroll
            for (int g2 = sg * 16; g2 < sg * 16 + 16; ++g2)
                s += red[(which * 128 + g2) * 36 + c];
            part[t] = s;
        }
        __syncthreads();
        // stage-2: agg_i (t<32) / agg_j (32..63) into vcur[240+t]
        if (t < 64) {
            const int which = t >> 5, c = t & 31;
            float s = 0.0f;
            #pragma unroll
            for (int sg = 0; sg < 8; ++sg) s += part[which * 256 + sg * 32 + c];
            vcur[FF + t] = s;
        }
        __syncthreads();
    }

    // ---- node tail for BOTH rows: nw read once per block ----
    {
        const int fg = t % 60, h = t / 60;   // h in [0,16), 19 k each
        if (t < 960) {
            const int f0 = fg * 4;
            float4 aA = make_float4(0.f, 0.f, 0.f, 0.f);
            float4 aB = make_float4(0.f, 0.f, 0.f, 0.f);
            const int k0 = h * 19;
            #pragma unroll
            for (int k = k0; k < k0 + 19; ++k) {
                const float4 w = *(const float4*)(nw + k * FF + f0);
                const float va = vA[k], vb = vB[k];
                aA.x += va * w.x; aA.y += va * w.y; aA.z += va * w.z; aA.w += va * w.w;
                aB.x += vb * w.x; aB.y += vb * w.y; aB.z += vb * w.z; aB.w += vb * w.w;
            }
            *(float4*)(redn + h * 240 + f0)        = aA;
            *(float4*)(redn + 3840 + h * 240 + f0) = aB;
        }
    }
    __syncthreads();
    if (t < FF) {
        float rA = nb[t], rB = nb[t];
        #pragma unroll
        for (int h = 0; h < 16; ++h) {
            rA += redn[h * 240 + t];
            rB += redn[3840 + h * 240 + t];
        }
        xout[base * FF + t]       = rA;
        xout[(base + 1) * FF + t] = rB;
        xsA[t] = rA;
        xsB[t] = rB;
    }
    if (DO_PQ) {
        __syncthreads();
        // PQ tail for BOTH rows: sw2 read once per block
        const int c = t & 31, isQ = (t >> 5) & 1, g = t >> 6;   // g in [0,16)
        const float* wb = sw2 + (isQ ? FF * CC : 0) + c;
        const float bias = (!isQ && g == 0) ? sb2[c] : 0.0f;
        float accA = bias, accB = bias;
        const int f0 = g * 15;
        #pragma unroll
        for (int f = f0; f < f0 + 15; ++f) {
            const float w = wb[f * CC];
            accA += xsA[f] * w;
            accB += xsB[f] * w;
        }
        red2[g * 64 + (t & 63)]        = accA;
        red2[1024 + g * 64 + (t & 63)] = accB;
        __syncthreads();
        if (t < 128) {
            const int row = t >> 6, slot = t & 63;
            float s = 0.0f;
            #pragma unroll
            for (int g2 = 0; g2 < 16; ++g2) s += red2[row * 1024 + g2 * 64 + slot];
            const int bb = base + row;
            if (slot >= 32) Qout[bb * CC + (slot & 31)] = s;
            else            Pout[bb * CC + slot] = s;
        }
    }
}

// ---------------------------------------------------------------------------
// K4: out[i][l] = db[l] + sum_f x2[i][f]*dw[f*L+l], 8 rows/block for dw reuse
// grid = (N/8, 6) blocks, 256 threads  (R8 version, measured-good)
// ---------------------------------------------------------------------------
__global__ __launch_bounds__(256) void dense_kernel(
    const float* __restrict__ x, const float* __restrict__ dw,
    const float* __restrict__ db, float* __restrict__ out) {
    const int i0 = blockIdx.x * 8;
    const int l  = blockIdx.y * 256 + threadIdx.x;
    __shared__ float xs[8][FF];
    for (int idx = threadIdx.x; idx < 8 * FF; idx += 256) {
        const int r = idx / FF, f = idx - r * FF;
        xs[r][f] = x[(i0 + r) * FF + f];
    }
    __syncthreads();
    if (l < LL) {
        float a0 = db[l], a1 = a0, a2 = a0, a3 = a0;
        float a4 = a0, a5 = a0, a6 = a0, a7 = a0;
        #pragma unroll 4
        for (int f = 0; f < FF; ++f) {
            const float w = dw[f * LL + l];
            a0 += xs[0][f] * w;
            a1 += xs[1][f] * w;
            a2 += xs[2][f] * w;
            a3 += xs[3][f] * w;
            a4 += xs[4][f] * w;
            a5 += xs[5][f] * w;
            a6 += xs[6][f] * w;
            a7 += xs[7][f] * w;
        }
        out[(i0 + 0) * LL + l] = a0;
        out[(i0 + 1) * LL + l] = a1;
        out[(i0 + 2) * LL + l] = a2;
        out[(i0 + 3) * LL + l] = a3;
        out[(i0 + 4) * LL + l] = a4;
        out[(i0 + 5) * LL + l] = a5;
        out[(i0 + 6) * LL + l] = a6;
        out[(i0 + 7) * LL + l] = a7;
    }
}

extern "C" void kernel_launch(void* const* d_in, const int* in_sizes, int n_in,
                              void* d_out, int out_size, void* d_ws, size_t ws_size,
                              hipStream_t stream) {
    const float* x  = (const float*)d_in[0];
    const float* a  = (const float*)d_in[1];
    const float* e0 = (const float*)d_in[2];

    const float* c1_sw  = (const float*)d_in[3];
    const float* c1_sb  = (const float*)d_in[4];
    const float* c1_aiw = (const float*)d_in[5];
    const float* c1_aib = (const float*)d_in[6];
    const float* c1_ajw = (const float*)d_in[7];
    const float* c1_ajb = (const float*)d_in[8];
    const float* c1_nw  = (const float*)d_in[9];
    const float* c1_nb  = (const float*)d_in[10];
    const float* c1_ew  = (const float*)d_in[11];
    const float* c1_eb  = (const float*)d_in[12];

    const float* c2_sw  = (const float*)d_in[13];
    const float* c2_sb  = (const float*)d_in[14];
    const float* c2_aiw = (const float*)d_in[15];
    const float* c2_aib = (const float*)d_in[16];
    const float* c2_ajw = (const float*)d_in[17];
    const float* c2_ajb = (const float*)d_in[18];
    const float* c2_nw  = (const float*)d_in[19];
    const float* c2_nb  = (const float*)d_in[20];
    // d_in[21]/d_in[22] (c2_ew/c2_eb): layer-2 edge output is dead code
    const float* dw = (const float*)d_in[23];
    const float* db = (const float*)d_in[24];

    float* ws = (float*)d_ws;
    float* P1 = ws;                 // 12800
    float* Q1 = ws + 12800;         // 12800
    float* P2 = ws + 25600;         // 12800
    float* Q2 = ws + 38400;         // 12800
    float* x1 = ws + 51200;         // 96000
    float* x2 = ws + 147200;        // 96000
    float* e1 = ws + 243200;        // 160000

    float* out = (float*)d_out;

    // K1: layer-1 P/Q projection (2 rows/block)
    pq_kernel<<<NN / 2, 256, 0, stream>>>(x, c1_sw, c1_sb, P1, Q1);

    // K2: layer-1 rcf + node model + layer-2 P/Q (2 rows/block)
    rcf_node<true, true><<<NN / 2, 1024, 0, stream>>>(
        P1, Q1, e0, a, c1_sw + 480 * CC,
        c1_aiw, c1_aib, c1_ajw, c1_ajb, c1_ew, c1_eb, e1,
        x, c1_nw, c1_nb, c2_sw, c2_sb, x1, P2, Q2);

    // K3: layer-2 rcf + node model (no e_out, no next PQ)
    rcf_node<false, false><<<NN / 2, 1024, 0, stream>>>(
        P2, Q2, e1, a, c2_sw + 480 * CC,
        c2_aiw, c2_aib, c2_ajw, c2_ajb, nullptr, nullptr, nullptr,
        x1, c2_nw, c2_nb, nullptr, nullptr, x2, nullptr, nullptr);

    // K4: final dense
    dense_kernel<<<dim3(NN / 8, 6), 256, 0, stream>>>(x2, dw, db, out);
}

// Round 11
// 58.228 us; speedup vs baseline: 1.2649x; 1.0960x over previous
//
#include <hip/hip_runtime.h>

#define NN 400
#define FF 240
#define CC 32
#define NIN 304   // F + 2C
#define LL 1440

// ---------------------------------------------------------------------------
// K1: P/Q projection, 4 rows per block (sw read once per 4 rows).
// grid = 100 blocks, 256 threads.
// ---------------------------------------------------------------------------
__global__ __launch_bounds__(256) void pq_kernel(
    const float* __restrict__ x, const float* __restrict__ sw,
    const float* __restrict__ sb, float* __restrict__ P, float* __restrict__ Q) {
    const int i0  = blockIdx.x * 4;
    const int t   = threadIdx.x;
    const int c   = t & 31;
    const int isQ = (t >> 5) & 1;
    const int g   = t >> 6;            // 0..3, 60 f each
    const float* wb = sw + (isQ ? FF * CC : 0) + c;
    const float bias = (!isQ && g == 0) ? sb[c] : 0.0f;
    float acc0 = bias, acc1 = bias, acc2 = bias, acc3 = bias;
    const float* xr = x + i0 * FF;
    const int f0 = g * 60;
    #pragma unroll 4
    for (int f = f0; f < f0 + 60; ++f) {
        const float w = wb[f * CC];
        acc0 += xr[f] * w;
        acc1 += xr[FF + f] * w;
        acc2 += xr[2 * FF + f] * w;
        acc3 += xr[3 * FF + f] * w;
    }
    __shared__ float red[4][256];
    const int slot = t & 63;
    red[g][slot]       = acc0;
    red[g][64 + slot]  = acc1;
    red[g][128 + slot] = acc2;
    red[g][192 + slot] = acc3;
    __syncthreads();
    {
        const int row = t >> 6, s2 = t & 63;
        const float s = red[0][row * 64 + s2] + red[1][row * 64 + s2]
                      + red[2][row * 64 + s2] + red[3][row * 64 + s2];
        const int i = i0 + row;
        if (s2 >= 32) Q[i * CC + (s2 & 31)] = s;
        else          P[i * CC + s2] = s;
    }
}

// ---------------------------------------------------------------------------
// K2/K3: one 1024-thread block per TWO rows (base, base+1; base even).
// XCD-swizzled. The column gathers e[k*NN+b], a[k*NN+b] for rows base/base+1
// are adjacent floats in one 64B line -> hoisted ONCE as float2, shared by
// both row-phases (halves gather transactions vs R10). Row-direction loads
// (e[b*NN+k], a[b*NN+k]) are coalesced and loaded in-phase.
// Per row-phase: rcf over all 400 k (4 its of 128 pairs), agg reduced in LDS.
// Then ONE node tail + ONE PQ tail for both rows.
// pg = t>>3 pair-group in [0,128), l = t&7 channel quad.
// ---------------------------------------------------------------------------
template<bool WRITE_E, bool DO_PQ>
__global__ __launch_bounds__(1024) void rcf_node(
    const float* __restrict__ P, const float* __restrict__ Q,
    const float* __restrict__ e, const float* __restrict__ a,
    const float* __restrict__ sw_tail,   // sw + 480*CC : rows [w1 ; w2]
    const float* __restrict__ aiw, const float* __restrict__ aib,
    const float* __restrict__ ajw, const float* __restrict__ ajb,
    const float* __restrict__ ew, const float* __restrict__ eb,
    float* __restrict__ e_out,
    const float* __restrict__ xin, const float* __restrict__ nw,
    const float* __restrict__ nb,
    const float* __restrict__ sw2, const float* __restrict__ sb2,
    float* __restrict__ xout, float* __restrict__ Pout, float* __restrict__ Qout) {
    // 200 blocks: (bid&7) selects XCD cluster of 50 rows; (bid>>3) in [0,25)
    const int bid  = blockIdx.x;
    const int base = (bid & 7) * 50 + (bid >> 3) * 2;   // even
    const int t  = threadIdx.x;
    const int pg = t >> 3, l = t & 7, c0 = l * 4;

    __shared__ float smem[10816];
    float* red  = smem;           // 9216 = 256*36 (rcf reduce; overlaid later)
    float* vA   = smem + 9216;    // 304
    float* vB   = smem + 9520;    // 304
    float* xsA  = smem + 9824;    // 240
    float* xsB  = smem + 10064;   // 240
    float* part = smem + 10304;   // 512
    float* redn = smem;           // 2*16*240 = 7680 (overlays red)
    float* red2 = smem;           // 2*16*64  = 2048 (overlays red)

    if (t < FF) {                 // stage both x-rows early
        vA[t] = xin[base * FF + t];
        vB[t] = xin[(base + 1) * FF + t];
    }

    // ---- hoisted SHARED column gathers (one float2 line serves both rows) ----
    float2 er2[4], ak2[4];
    int kk[4];
    #pragma unroll
    for (int it = 0; it < 4; ++it) {
        const int off = it * 128 + pg;
        kk[it] = (off < NN) ? off : 0;
        er2[it] = *(const float2*)(e + kk[it] * NN + base);
        ak2[it] = *(const float2*)(a + kk[it] * NN + base);
    }

    // weights shared across both row-phases
    float w1v[4], w2v[4], wiv[4], wjv[4], wev[4];
    *(float4*)w1v = *(const float4*)(sw_tail + c0);
    *(float4*)w2v = *(const float4*)(sw_tail + CC + c0);
    *(float4*)wiv = *(const float4*)(aiw + c0);
    *(float4*)wjv = *(const float4*)(ajw + c0);
    if (WRITE_E) *(float4*)wev = *(const float4*)(ew + c0);
    const float bi = aib[0], bj = ajb[0];
    const float be = WRITE_E ? eb[0] : 0.0f;

    #pragma unroll
    for (int rp = 0; rp < 2; ++rp) {
        const int b = base + rp;
        float* vcur = rp ? vB : vA;

        float Pb[4], Qb[4];
        *(float4*)Pb = *(const float4*)(P + b * CC + c0);
        *(float4*)Qb = *(const float4*)(Q + b * CC + c0);

        float acc_i[4] = {0, 0, 0, 0}, acc_j[4] = {0, 0, 0, 0};
        #pragma unroll
        for (int it = 0; it < 4; ++it) {
            const int off = it * 128 + pg;
            const bool valid = off < NN;
            const int k = kk[it];
            float Qk[4], Pk[4];
            *(float4*)Qk = *(const float4*)(Q + k * CC + c0);
            *(float4*)Pk = *(const float4*)(P + k * CC + c0);
            const float e_f  = e[b * NN + k];                    // coalesced
            const float a_bk = a[b * NN + k];                    // coalesced
            const float e_r  = rp ? er2[it].y : er2[it].x;       // shared gather
            const float a_kb = rp ? ak2[it].y : ak2[it].x;       // shared gather
            float sr[4], sc[4];
            #pragma unroll
            for (int q = 0; q < 4; ++q) {
                sr[q] = fmaxf(Pb[q] + Qk[q] + e_f * w1v[q] + e_r * w2v[q], 0.0f) * a_bk;
                sc[q] = fmaxf(Pk[q] + Qb[q] + e_r * w1v[q] + e_f * w2v[q], 0.0f) * a_kb;
            }
            float d_i = sr[0] * wiv[0] + sr[1] * wiv[1] + sr[2] * wiv[2] + sr[3] * wiv[3];
            float d_j = sc[0] * wjv[0] + sc[1] * wjv[1] + sc[2] * wjv[2] + sc[3] * wjv[3];
            float d_e = WRITE_E ? (sr[0] * wev[0] + sr[1] * wev[1] + sr[2] * wev[2] + sr[3] * wev[3]) : 0.0f;
            #pragma unroll
            for (int m = 1; m < 8; m <<= 1) {
                d_i += __shfl_xor(d_i, m);
                d_j += __shfl_xor(d_j, m);
                if (WRITE_E) d_e += __shfl_xor(d_e, m);
            }
            const float gi = valid ? __fdividef(1.0f, 1.0f + __expf(-(d_i + bi))) : 0.0f;
            const float gj = valid ? __fdividef(1.0f, 1.0f + __expf(-(d_j + bj))) : 0.0f;
            #pragma unroll
            for (int q = 0; q < 4; ++q) {
                acc_i[q] += gi * sr[q];
                acc_j[q] += gj * sc[q];
            }
            if (WRITE_E && l == 0 && valid) e_out[b * NN + k] = d_e + be;
        }
        #pragma unroll
        for (int q = 0; q < 4; ++q) {
            red[pg * 36 + c0 + q]          = acc_i[q];
            red[(128 + pg) * 36 + c0 + q]  = acc_j[q];
        }
        __syncthreads();
        // stage-1: 512 threads each sum 16 pair-groups
        if (t < 512) {
            const int c = t & 31, sg = (t >> 5) & 7, which = t >> 8;
            float s = 0.0f;
            #pragma unroll
            for (int g2 = sg * 16; g2 < sg * 16 + 16; ++g2)
                s += red[(which * 128 + g2) * 36 + c];
            part[t] = s;
        }
        __syncthreads();
        // stage-2: agg_i (t<32) / agg_j (32..63) into vcur[240+t]
        if (t < 64) {
            const int which = t >> 5, c = t & 31;
            float s = 0.0f;
            #pragma unroll
            for (int sg = 0; sg < 8; ++sg) s += part[which * 256 + sg * 32 + c];
            vcur[FF + t] = s;
        }
        __syncthreads();
    }

    // ---- node tail for BOTH rows: nw read once per block ----
    {
        const int fg = t % 60, h = t / 60;   // h in [0,16), 19 k each
        if (t < 960) {
            const int f0 = fg * 4;
            float4 aA = make_float4(0.f, 0.f, 0.f, 0.f);
            float4 aB = make_float4(0.f, 0.f, 0.f, 0.f);
            const int k0 = h * 19;
            #pragma unroll
            for (int k = k0; k < k0 + 19; ++k) {
                const float4 w = *(const float4*)(nw + k * FF + f0);
                const float va = vA[k], vb = vB[k];
                aA.x += va * w.x; aA.y += va * w.y; aA.z += va * w.z; aA.w += va * w.w;
                aB.x += vb * w.x; aB.y += vb * w.y; aB.z += vb * w.z; aB.w += vb * w.w;
            }
            *(float4*)(redn + h * 240 + f0)        = aA;
            *(float4*)(redn + 3840 + h * 240 + f0) = aB;
        }
    }
    __syncthreads();
    if (t < FF) {
        float rA = nb[t], rB = nb[t];
        #pragma unroll
        for (int h = 0; h < 16; ++h) {
            rA += redn[h * 240 + t];
            rB += redn[3840 + h * 240 + t];
        }
        xout[base * FF + t]       = rA;
        xout[(base + 1) * FF + t] = rB;
        xsA[t] = rA;
        xsB[t] = rB;
    }
    if (DO_PQ) {
        __syncthreads();
        // PQ tail for BOTH rows: sw2 read once per block
        const int c = t & 31, isQ = (t >> 5) & 1, g = t >> 6;   // g in [0,16)
        const float* wb = sw2 + (isQ ? FF * CC : 0) + c;
        const float bias = (!isQ && g == 0) ? sb2[c] : 0.0f;
        float accA = bias, accB = bias;
        const int f0 = g * 15;
        #pragma unroll
        for (int f = f0; f < f0 + 15; ++f) {
            const float w = wb[f * CC];
            accA += xsA[f] * w;
            accB += xsB[f] * w;
        }
        red2[g * 64 + (t & 63)]        = accA;
        red2[1024 + g * 64 + (t & 63)] = accB;
        __syncthreads();
        if (t < 128) {
            const int row = t >> 6, slot = t & 63;
            float s = 0.0f;
            #pragma unroll
            for (int g2 = 0; g2 < 16; ++g2) s += red2[row * 1024 + g2 * 64 + slot];
            const int bb = base + row;
            if (slot >= 32) Qout[bb * CC + (slot & 31)] = s;
            else            Pout[bb * CC + slot] = s;
        }
    }
}

// ---------------------------------------------------------------------------
// K4: out[i][l] = db[l] + sum_f x2[i][f]*dw[f*L+l], 8 rows/block for dw reuse
// grid = (N/8, 6) blocks, 256 threads  (R8 version, measured-good)
// ---------------------------------------------------------------------------
__global__ __launch_bounds__(256) void dense_kernel(
    const float* __restrict__ x, const float* __restrict__ dw,
    const float* __restrict__ db, float* __restrict__ out) {
    const int i0 = blockIdx.x * 8;
    const int l  = blockIdx.y * 256 + threadIdx.x;
    __shared__ float xs[8][FF];
    for (int idx = threadIdx.x; idx < 8 * FF; idx += 256) {
        const int r = idx / FF, f = idx - r * FF;
        xs[r][f] = x[(i0 + r) * FF + f];
    }
    __syncthreads();
    if (l < LL) {
        float a0 = db[l], a1 = a0, a2 = a0, a3 = a0;
        float a4 = a0, a5 = a0, a6 = a0, a7 = a0;
        #pragma unroll 4
        for (int f = 0; f < FF; ++f) {
            const float w = dw[f * LL + l];
            a0 += xs[0][f] * w;
            a1 += xs[1][f] * w;
            a2 += xs[2][f] * w;
            a3 += xs[3][f] * w;
            a4 += xs[4][f] * w;
            a5 += xs[5][f] * w;
            a6 += xs[6][f] * w;
            a7 += xs[7][f] * w;
        }
        out[(i0 + 0) * LL + l] = a0;
        out[(i0 + 1) * LL + l] = a1;
        out[(i0 + 2) * LL + l] = a2;
        out[(i0 + 3) * LL + l] = a3;
        out[(i0 + 4) * LL + l] = a4;
        out[(i0 + 5) * LL + l] = a5;
        out[(i0 + 6) * LL + l] = a6;
        out[(i0 + 7) * LL + l] = a7;
    }
}

extern "C" void kernel_launch(void* const* d_in, const int* in_sizes, int n_in,
                              void* d_out, int out_size, void* d_ws, size_t ws_size,
                              hipStream_t stream) {
    const float* x  = (const float*)d_in[0];
    const float* a  = (const float*)d_in[1];
    const float* e0 = (const float*)d_in[2];

    const float* c1_sw  = (const float*)d_in[3];
    const float* c1_sb  = (const float*)d_in[4];
    const float* c1_aiw = (const float*)d_in[5];
    const float* c1_aib = (const float*)d_in[6];
    const float* c1_ajw = (const float*)d_in[7];
    const float* c1_ajb = (const float*)d_in[8];
    const float* c1_nw  = (const float*)d_in[9];
    const float* c1_nb  = (const float*)d_in[10];
    const float* c1_ew  = (const float*)d_in[11];
    const float* c1_eb  = (const float*)d_in[12];

    const float* c2_sw  = (const float*)d_in[13];
    const float* c2_sb  = (const float*)d_in[14];
    const float* c2_aiw = (const float*)d_in[15];
    const float* c2_aib = (const float*)d_in[16];
    const float* c2_ajw = (const float*)d_in[17];
    const float* c2_ajb = (const float*)d_in[18];
    const float* c2_nw  = (const float*)d_in[19];
    const float* c2_nb  = (const float*)d_in[20];
    // d_in[21]/d_in[22] (c2_ew/c2_eb): layer-2 edge output is dead code
    const float* dw = (const float*)d_in[23];
    const float* db = (const float*)d_in[24];

    float* ws = (float*)d_ws;
    float* P1 = ws;                 // 12800
    float* Q1 = ws + 12800;         // 12800
    float* P2 = ws + 25600;         // 12800
    float* Q2 = ws + 38400;         // 12800
    float* x1 = ws + 51200;         // 96000
    float* x2 = ws + 147200;        // 96000
    float* e1 = ws + 243200;        // 160000

    float* out = (float*)d_out;

    // K1: layer-1 P/Q projection (4 rows/block)
    pq_kernel<<<NN / 4, 256, 0, stream>>>(x, c1_sw, c1_sb, P1, Q1);

    // K2: layer-1 rcf + node model + layer-2 P/Q (2 rows/block, shared gathers)
    rcf_node<true, true><<<NN / 2, 1024, 0, stream>>>(
        P1, Q1, e0, a, c1_sw + 480 * CC,
        c1_aiw, c1_aib, c1_ajw, c1_ajb, c1_ew, c1_eb, e1,
        x, c1_nw, c1_nb, c2_sw, c2_sb, x1, P2, Q2);

    // K3: layer-2 rcf + node model (no e_out, no next PQ)
    rcf_node<false, false><<<NN / 2, 1024, 0, stream>>>(
        P2, Q2, e1, a, c2_sw + 480 * CC,
        c2_aiw, c2_aib, c2_ajw, c2_ajb, nullptr, nullptr, nullptr,
        x1, c2_nw, c2_nb, nullptr, nullptr, x2, nullptr, nullptr);

    // K4: final dense
    dense_kernel<<<dim3(NN / 8, 6), 256, 0, stream>>>(x2, dw, db, out);
}